// Round 1
// baseline (98.960 us; speedup 1.0000x reference)
//
#include <hip/hip_runtime.h>

#define N 256
#define D 2048
#define MARGIN_F 0.3f
#define EPS_F 1e-12f

// ---------------- kernel 0: sq[i] = sum_k x[i][k]^2 -------------------------
__global__ __launch_bounds__(64) void sq_kernel(const float* __restrict__ x,
                                                float* __restrict__ sq) {
    int row = blockIdx.x;
    int lane = threadIdx.x;
    const float4* xr = (const float4*)(x + (size_t)row * D);
    float acc = 0.f;
#pragma unroll
    for (int it = 0; it < 8; ++it) {
        float4 v = xr[lane + 64 * it];
        acc += v.x * v.x + v.y * v.y + v.z * v.z + v.w * v.w;
    }
#pragma unroll
    for (int off = 32; off > 0; off >>= 1) acc += __shfl_down(acc, off, 64);
    if (lane == 0) sq[row] = acc;
}

// ---------------- kernel 1: Gram partials (K-split 64) ----------------------
// grid (2,2,64): tile (bi,bj) of 128x128, K-chunk of 32.
// LDS layout: rows of 32 floats (128B, == 32 banks, so row start bank is
// always 0); float4 column index XOR-swizzled with (row>>3)&7 so the 8x8
// register-tile reads hit distinct bank quads (<=2-way, free).
__global__ __launch_bounds__(256, 1) void gram_kernel(const float* __restrict__ x,
                                                      float* __restrict__ part) {
    __shared__ __align__(16) float As[128 * 32];
    __shared__ __align__(16) float Bs[128 * 32];
    const int bi = blockIdx.x, bj = blockIdx.y, ks = blockIdx.z;
    const int i0 = bi * 128, j0 = bj * 128, k0 = ks * 32;
    const int tid = threadIdx.x;

    // Stage A and B chunks: 128 rows x 8 float4 each.
#pragma unroll
    for (int it = 0; it < 4; ++it) {
        int f = tid + 256 * it;      // 0..1023
        int row = f >> 3;
        int c4 = f & 7;
        int sc4 = c4 ^ ((row >> 3) & 7);
        float4 va = *(const float4*)(x + (size_t)(i0 + row) * D + k0 + c4 * 4);
        float4 vb = *(const float4*)(x + (size_t)(j0 + row) * D + k0 + c4 * 4);
        *(float4*)(As + row * 32 + sc4 * 4) = va;
        *(float4*)(Bs + row * 32 + sc4 * 4) = vb;
    }
    __syncthreads();

    const int tx = tid & 15;    // j sub-tile
    const int ty = tid >> 4;    // i sub-tile
    float acc[8][8];
#pragma unroll
    for (int r = 0; r < 8; ++r)
#pragma unroll
        for (int c = 0; c < 8; ++c) acc[r][c] = 0.f;

#pragma unroll
    for (int k4 = 0; k4 < 8; ++k4) {
        float4 a[8], b[8];
#pragma unroll
        for (int r = 0; r < 8; ++r) {
            int ia = ty * 8 + r;
            int ib = tx * 8 + r;
            a[r] = *(const float4*)(As + ia * 32 + ((k4 ^ ((ia >> 3) & 7)) << 2));
            b[r] = *(const float4*)(Bs + ib * 32 + ((k4 ^ ((ib >> 3) & 7)) << 2));
        }
#pragma unroll
        for (int r = 0; r < 8; ++r)
#pragma unroll
            for (int c = 0; c < 8; ++c)
                acc[r][c] += a[r].x * b[c].x + a[r].y * b[c].y +
                             a[r].z * b[c].z + a[r].w * b[c].w;
    }

    float* pout = part + (size_t)ks * (N * N);
#pragma unroll
    for (int r = 0; r < 8; ++r) {
        int gi = i0 + ty * 8 + r;
#pragma unroll
        for (int c = 0; c < 8; c += 4) {
            float4 v = make_float4(acc[r][c], acc[r][c + 1], acc[r][c + 2], acc[r][c + 3]);
            *(float4*)(pout + (size_t)gi * N + j0 + tx * 8 + c) = v;
        }
    }
}

// ---------------- kernel 2: reduce partials -> dist -------------------------
__global__ __launch_bounds__(64) void reduce_kernel(const float* __restrict__ part,
                                                    const float* __restrict__ sq,
                                                    float* __restrict__ dist) {
    int t = blockIdx.x * 64 + threadIdx.x;   // 0..16383 (float4 index)
    float4 acc = make_float4(0.f, 0.f, 0.f, 0.f);
#pragma unroll 8
    for (int ks = 0; ks < 64; ++ks) {
        float4 v = *(const float4*)(part + (size_t)ks * (N * N) + (size_t)t * 4);
        acc.x += v.x; acc.y += v.y; acc.z += v.z; acc.w += v.w;
    }
    int i = t >> 6;
    int j4 = (t & 63) * 4;
    float si = sq[i];
    float4 sj = *(const float4*)(sq + j4);
    float4 d;
    d.x = sqrtf(fmaxf(si + sj.x - 2.f * acc.x, EPS_F));
    d.y = sqrtf(fmaxf(si + sj.y - 2.f * acc.y, EPS_F));
    d.z = sqrtf(fmaxf(si + sj.z - 2.f * acc.z, EPS_F));
    d.w = sqrtf(fmaxf(si + sj.w - 2.f * acc.w, EPS_F));
    *(float4*)(dist + (size_t)t * 4) = d;
}

// ---------------- kernel 3: broadcast triplet output ------------------------
// grid (256, 16): a = blockIdx.x, p-range = [16*blockIdx.y, +16).
// thread: lane = tid&63 owns n4 = lane*4..+3; pq = tid>>6 picks 4 p values.
__global__ __launch_bounds__(256) void triplet_kernel(const float* __restrict__ dist,
                                                      const int* __restrict__ targets,
                                                      float* __restrict__ out) {
    __shared__ __align__(16) float drow[N];
    __shared__ int lab[N];
    const int a = blockIdx.x;
    const int p0 = blockIdx.y * 16;
    const int tid = threadIdx.x;
    lab[tid] = targets[tid];
    drow[tid] = dist[a * N + tid];
    __syncthreads();

    const int la = lab[a];
    const int lane = tid & 63;
    const int pq = tid >> 6;

    float4 dan = *(const float4*)(drow + lane * 4);
    // mb = MARGIN - d(a,n); tri = d(a,p) + mb
    float4 mb = make_float4(MARGIN_F - dan.x, MARGIN_F - dan.y,
                            MARGIN_F - dan.z, MARGIN_F - dan.w);
    float nok_x = (lab[lane * 4 + 0] != la) ? 1.f : 0.f;
    float nok_y = (lab[lane * 4 + 1] != la) ? 1.f : 0.f;
    float nok_z = (lab[lane * 4 + 2] != la) ? 1.f : 0.f;
    float nok_w = (lab[lane * 4 + 3] != la) ? 1.f : 0.f;

    float* obase = out + ((size_t)a << 16) + lane * 4;
#pragma unroll
    for (int j = 0; j < 4; ++j) {
        int p = p0 + pq * 4 + j;          // wave-uniform
        float4 r;
        if (lab[p] == la) {               // wave-uniform branch
            float dap = drow[p];
            r.x = fmaxf(dap + mb.x, EPS_F) * nok_x;
            r.y = fmaxf(dap + mb.y, EPS_F) * nok_y;
            r.z = fmaxf(dap + mb.z, EPS_F) * nok_z;
            r.w = fmaxf(dap + mb.w, EPS_F) * nok_w;
        } else {
            r = make_float4(0.f, 0.f, 0.f, 0.f);
        }
        *(float4*)(obase + (size_t)p * N) = r;
    }
}

extern "C" void kernel_launch(void* const* d_in, const int* in_sizes, int n_in,
                              void* d_out, int out_size, void* d_ws, size_t ws_size,
                              hipStream_t stream) {
    const float* x = (const float*)d_in[0];
    const int* targets = (const int*)d_in[1];
    float* out = (float*)d_out;
    float* ws = (float*)d_ws;

    float* sq = ws;                // 256 floats
    float* dist = ws + 256;        // 65536 floats
    size_t need = (size_t)(256 + N * N + 64 * N * N) * sizeof(float);
    // Partials (16 MB): use ws if it's big enough, else borrow d_out as
    // scratch (safe: reduce_kernel finishes before triplet_kernel overwrites
    // every element of out, all on the same stream).
    float* part = (ws_size >= need) ? (ws + 256 + N * N) : (float*)d_out;

    sq_kernel<<<256, 64, 0, stream>>>(x, sq);
    gram_kernel<<<dim3(2, 2, 64), 256, 0, stream>>>(x, part);
    reduce_kernel<<<256, 64, 0, stream>>>(part, sq, dist);
    triplet_kernel<<<dim3(256, 16), 256, 0, stream>>>(dist, targets, out);
}

// Round 2
// 95.654 us; speedup vs baseline: 1.0346x; 1.0346x over previous
//
#include <hip/hip_runtime.h>
#include <hip/hip_fp16.h>

#define N 256
#define D 2048
#define MARGIN_F 0.3f
#define EPS_F 1e-12f

typedef float v4f __attribute__((ext_vector_type(4)));

// ---------------- kernel 0: sq[i] = sum_k x[i][k]^2 -------------------------
__global__ __launch_bounds__(64) void sq_kernel(const float* __restrict__ x,
                                                float* __restrict__ sq) {
    int row = blockIdx.x;
    int lane = threadIdx.x;
    const float4* xr = (const float4*)(x + (size_t)row * D);
    float acc = 0.f;
#pragma unroll
    for (int it = 0; it < 8; ++it) {
        float4 v = xr[lane + 64 * it];
        acc += v.x * v.x + v.y * v.y + v.z * v.z + v.w * v.w;
    }
#pragma unroll
    for (int off = 32; off > 0; off >>= 1) acc += __shfl_down(acc, off, 64);
    if (lane == 0) sq[row] = acc;
}

// ---------------- kernel 1: Gram partials (K-split 64, fp16 out) ------------
// grid (2,2,64): tile (bi,bj) of 128x128, K-chunk of 32. XOR-swizzled LDS,
// 8x8 register tile per thread. Partials stored as fp16 (|partial| <~30,
// rel err 4.9e-4 -> dist err ~0.002, threshold 0.126).
__global__ __launch_bounds__(256, 1) void gram_kernel(const float* __restrict__ x,
                                                      __half* __restrict__ part) {
    __shared__ __align__(16) float As[128 * 32];
    __shared__ __align__(16) float Bs[128 * 32];
    const int bi = blockIdx.x, bj = blockIdx.y, ks = blockIdx.z;
    const int i0 = bi * 128, j0 = bj * 128, k0 = ks * 32;
    const int tid = threadIdx.x;

#pragma unroll
    for (int it = 0; it < 4; ++it) {
        int f = tid + 256 * it;      // 0..1023
        int row = f >> 3;
        int c4 = f & 7;
        int sc4 = c4 ^ ((row >> 3) & 7);
        float4 va = *(const float4*)(x + (size_t)(i0 + row) * D + k0 + c4 * 4);
        float4 vb = *(const float4*)(x + (size_t)(j0 + row) * D + k0 + c4 * 4);
        *(float4*)(As + row * 32 + sc4 * 4) = va;
        *(float4*)(Bs + row * 32 + sc4 * 4) = vb;
    }
    __syncthreads();

    const int tx = tid & 15;    // j sub-tile
    const int ty = tid >> 4;    // i sub-tile
    float acc[8][8];
#pragma unroll
    for (int r = 0; r < 8; ++r)
#pragma unroll
        for (int c = 0; c < 8; ++c) acc[r][c] = 0.f;

#pragma unroll
    for (int k4 = 0; k4 < 8; ++k4) {
        float4 a[8], b[8];
#pragma unroll
        for (int r = 0; r < 8; ++r) {
            int ia = ty * 8 + r;
            int ib = tx * 8 + r;
            a[r] = *(const float4*)(As + ia * 32 + ((k4 ^ ((ia >> 3) & 7)) << 2));
            b[r] = *(const float4*)(Bs + ib * 32 + ((k4 ^ ((ib >> 3) & 7)) << 2));
        }
#pragma unroll
        for (int r = 0; r < 8; ++r)
#pragma unroll
            for (int c = 0; c < 8; ++c)
                acc[r][c] += a[r].x * b[c].x + a[r].y * b[c].y +
                             a[r].z * b[c].z + a[r].w * b[c].w;
    }

    __half* pout = part + (size_t)ks * (N * N);
#pragma unroll
    for (int r = 0; r < 8; ++r) {
        int gi = i0 + ty * 8 + r;
        union { __half2 h2[4]; uint4 u; } pk;
#pragma unroll
        for (int c = 0; c < 4; ++c)
            pk.h2[c] = __floats2half2_rn(acc[r][2 * c], acc[r][2 * c + 1]);
        *(uint4*)(pout + (size_t)gi * N + j0 + tx * 8) = pk.u;
    }
}

// ---------------- kernel 2: fused reduce + dist + triplet -------------------
// grid (256, 2): block = (anchor a, half of p-range). Phase 1: reduce 64 fp16
// partial slices for row a, build dist row in LDS. Phase 2: stream the output
// strip with nontemporal float4 stores.
__global__ __launch_bounds__(256) void fused_kernel(const __half* __restrict__ part,
                                                    const float* __restrict__ sq,
                                                    const int* __restrict__ targets,
                                                    float* __restrict__ out) {
    __shared__ __align__(16) float drow[N];
    __shared__ int lab[N];
    const int a = blockIdx.x;
    const int tid = threadIdx.x;
    lab[tid] = targets[tid];

    float dot = 0.f;
    const __half* base = part + a * N + tid;
#pragma unroll 8
    for (int ks = 0; ks < 64; ++ks)
        dot += __half2float(base[(size_t)ks * (N * N)]);
    drow[tid] = sqrtf(fmaxf(sq[a] + sq[tid] - 2.f * dot, EPS_F));
    __syncthreads();

    const int la = lab[a];
    const int lane = tid & 63;
    const int pq = tid >> 6;
    const int p0 = blockIdx.y * 128 + pq * 32;

    v4f dan = *(const v4f*)(drow + lane * 4);
    v4f mb = MARGIN_F - dan;
    v4f nokv = {(lab[lane * 4 + 0] != la) ? 1.f : 0.f,
                (lab[lane * 4 + 1] != la) ? 1.f : 0.f,
                (lab[lane * 4 + 2] != la) ? 1.f : 0.f,
                (lab[lane * 4 + 3] != la) ? 1.f : 0.f};

    float* obase = out + ((size_t)a << 16) + lane * 4;
#pragma unroll 4
    for (int i = 0; i < 32; ++i) {
        int p = p0 + i;                   // wave-uniform
        v4f r = {0.f, 0.f, 0.f, 0.f};
        if (lab[p] == la) {               // wave-uniform branch
            float dap = drow[p];
            v4f t = dap + mb;
            t.x = fmaxf(t.x, EPS_F);
            t.y = fmaxf(t.y, EPS_F);
            t.z = fmaxf(t.z, EPS_F);
            t.w = fmaxf(t.w, EPS_F);
            r = t * nokv;
        }
        __builtin_nontemporal_store(r, (v4f*)(obase + (size_t)p * N));
    }
}

// ---------------- fallback path (tiny ws): dist kernel + old triplet --------
__global__ __launch_bounds__(256) void dist_kernel(const __half* __restrict__ part,
                                                   const float* __restrict__ sq,
                                                   float* __restrict__ dist) {
    const int a = blockIdx.x;
    const int tid = threadIdx.x;
    float dot = 0.f;
    const __half* base = part + a * N + tid;
#pragma unroll 8
    for (int ks = 0; ks < 64; ++ks)
        dot += __half2float(base[(size_t)ks * (N * N)]);
    dist[a * N + tid] = sqrtf(fmaxf(sq[a] + sq[tid] - 2.f * dot, EPS_F));
}

__global__ __launch_bounds__(256) void triplet_kernel(const float* __restrict__ dist,
                                                      const int* __restrict__ targets,
                                                      float* __restrict__ out) {
    __shared__ __align__(16) float drow[N];
    __shared__ int lab[N];
    const int a = blockIdx.x;
    const int p0 = blockIdx.y * 16;
    const int tid = threadIdx.x;
    lab[tid] = targets[tid];
    drow[tid] = dist[a * N + tid];
    __syncthreads();

    const int la = lab[a];
    const int lane = tid & 63;
    const int pq = tid >> 6;

    v4f dan = *(const v4f*)(drow + lane * 4);
    v4f mb = MARGIN_F - dan;
    v4f nokv = {(lab[lane * 4 + 0] != la) ? 1.f : 0.f,
                (lab[lane * 4 + 1] != la) ? 1.f : 0.f,
                (lab[lane * 4 + 2] != la) ? 1.f : 0.f,
                (lab[lane * 4 + 3] != la) ? 1.f : 0.f};

    float* obase = out + ((size_t)a << 16) + lane * 4;
#pragma unroll
    for (int j = 0; j < 4; ++j) {
        int p = p0 + pq * 4 + j;
        v4f r = {0.f, 0.f, 0.f, 0.f};
        if (lab[p] == la) {
            float dap = drow[p];
            v4f t = dap + mb;
            t.x = fmaxf(t.x, EPS_F);
            t.y = fmaxf(t.y, EPS_F);
            t.z = fmaxf(t.z, EPS_F);
            t.w = fmaxf(t.w, EPS_F);
            r = t * nokv;
        }
        __builtin_nontemporal_store(r, (v4f*)(obase + (size_t)p * N));
    }
}

extern "C" void kernel_launch(void* const* d_in, const int* in_sizes, int n_in,
                              void* d_out, int out_size, void* d_ws, size_t ws_size,
                              hipStream_t stream) {
    const float* x = (const float*)d_in[0];
    const int* targets = (const int*)d_in[1];
    float* out = (float*)d_out;
    float* ws = (float*)d_ws;

    float* sq = ws;                                    // 256 floats
    size_t need_full = 1024 + (size_t)64 * N * N * sizeof(__half) + 1024;  // ~8 MB

    if (ws_size >= need_full) {
        __half* part = (__half*)(ws + 256);
        sq_kernel<<<256, 64, 0, stream>>>(x, sq);
        gram_kernel<<<dim3(2, 2, 64), 256, 0, stream>>>(x, part);
        fused_kernel<<<dim3(256, 2), 256, 0, stream>>>(part, sq, targets, out);
    } else {
        // Borrow d_out (8 MB of its 64 MB) for partials; dist lives in ws.
        // Safe: dist_kernel consumes partials before triplet_kernel writes out.
        __half* part = (__half*)d_out;
        float* dist = ws + 256;                        // 65536 floats
        sq_kernel<<<256, 64, 0, stream>>>(x, sq);
        gram_kernel<<<dim3(2, 2, 64), 256, 0, stream>>>(x, part);
        dist_kernel<<<256, 256, 0, stream>>>(part, sq, dist);
        triplet_kernel<<<dim3(256, 16), 256, 0, stream>>>(dist, targets, out);
    }
}

// Round 3
// 92.464 us; speedup vs baseline: 1.0702x; 1.0345x over previous
//
#include <hip/hip_runtime.h>
#include <hip/hip_fp16.h>

#define N 256
#define D 2048
#define MARGIN_F 0.3f
#define EPS_F 1e-12f
#define SQRT_EPS_F 1e-6f

typedef float v4f __attribute__((ext_vector_type(4)));

// ---------------- kernel 0: sq[i] = sum_k x[i][k]^2 -------------------------
__global__ __launch_bounds__(64) void sq_kernel(const float* __restrict__ x,
                                                float* __restrict__ sq) {
    int row = blockIdx.x;
    int lane = threadIdx.x;
    const float4* xr = (const float4*)(x + (size_t)row * D);
    float acc = 0.f;
#pragma unroll
    for (int it = 0; it < 8; ++it) {
        float4 v = xr[lane + 64 * it];
        acc += v.x * v.x + v.y * v.y + v.z * v.z + v.w * v.w;
    }
#pragma unroll
    for (int off = 32; off > 0; off >>= 1) acc += __shfl_down(acc, off, 64);
    if (lane == 0) sq[row] = acc;
}

// ---------------- kernel 1: Gram partials, 64x64x64 tiles -------------------
// grid (4,4,32) = 512 blocks (2/CU). K-chunk 64 -> 32 fp16 slices = 4 MB.
// LDS rows padded to 68 floats; float4 column XOR-swizzled with (row>>2)&15
// so B-fragment ds_read_b128 spreads over all 8 bank quads (2-way = free).
__global__ __launch_bounds__(256) void gram_kernel(const float* __restrict__ x,
                                                   __half* __restrict__ part) {
    __shared__ __align__(16) float As[64 * 68];
    __shared__ __align__(16) float Bs[64 * 68];
    const int i0 = blockIdx.x * 64, j0 = blockIdx.y * 64, k0 = blockIdx.z * 64;
    const int tid = threadIdx.x;

#pragma unroll
    for (int it = 0; it < 4; ++it) {
        int f = tid + 256 * it;      // 0..1023
        int row = f >> 4;            // 0..63
        int c4 = f & 15;
        int sc4 = c4 ^ ((row >> 2) & 15);
        float4 va = *(const float4*)(x + (size_t)(i0 + row) * D + k0 + c4 * 4);
        float4 vb = *(const float4*)(x + (size_t)(j0 + row) * D + k0 + c4 * 4);
        *(float4*)(As + row * 68 + sc4 * 4) = va;
        *(float4*)(Bs + row * 68 + sc4 * 4) = vb;
    }
    __syncthreads();

    const int tx = tid & 15;    // j sub-tile (4 cols)
    const int ty = tid >> 4;    // i sub-tile (4 rows)
    float acc[4][4];
#pragma unroll
    for (int r = 0; r < 4; ++r)
#pragma unroll
        for (int c = 0; c < 4; ++c) acc[r][c] = 0.f;

#pragma unroll
    for (int k4 = 0; k4 < 16; ++k4) {
        float4 a[4], b[4];
        const int ca = (k4 ^ ty) << 2;   // (ty*4+r)>>2 == ty
        const int cb = (k4 ^ tx) << 2;   // (tx*4+c)>>2 == tx
#pragma unroll
        for (int r = 0; r < 4; ++r) {
            a[r] = *(const float4*)(As + (ty * 4 + r) * 68 + ca);
            b[r] = *(const float4*)(Bs + (tx * 4 + r) * 68 + cb);
        }
#pragma unroll
        for (int r = 0; r < 4; ++r)
#pragma unroll
            for (int c = 0; c < 4; ++c)
                acc[r][c] += a[r].x * b[c].x + a[r].y * b[c].y +
                             a[r].z * b[c].z + a[r].w * b[c].w;
    }

    __half* pout = part + (size_t)blockIdx.z * (N * N);
#pragma unroll
    for (int r = 0; r < 4; ++r) {
        int gi = i0 + ty * 4 + r;
        union { __half2 h2[2]; uint2 u; } pk;
        pk.h2[0] = __floats2half2_rn(acc[r][0], acc[r][1]);
        pk.h2[1] = __floats2half2_rn(acc[r][2], acc[r][3]);
        *(uint2*)(pout + (size_t)gi * N + j0 + tx * 4) = pk.u;
    }
}

// ---------------- kernel 2: fused reduce + dist + triplet -------------------
// grid (256, 2): block = (anchor a, half of p-range). Phase 1: reduce 32 fp16
// partial slices for row a -> dist row in LDS (diag forced to sqrt(eps) —
// replicates the reference's eps-clip branch, removes fp16 diag-noise risk).
// Phase 2: stream output strip with nontemporal float4 stores.
__global__ __launch_bounds__(256) void fused_kernel(const __half* __restrict__ part,
                                                    const float* __restrict__ sq,
                                                    const int* __restrict__ targets,
                                                    float* __restrict__ out) {
    __shared__ __align__(16) float drow[N];
    __shared__ int lab[N];
    const int a = blockIdx.x;
    const int tid = threadIdx.x;
    lab[tid] = targets[tid];

    float dot = 0.f;
    const __half* base = part + a * N + tid;
#pragma unroll 8
    for (int ks = 0; ks < 32; ++ks)
        dot += __half2float(base[(size_t)ks * (N * N)]);
    drow[tid] = (tid == a) ? SQRT_EPS_F
                           : sqrtf(fmaxf(sq[a] + sq[tid] - 2.f * dot, EPS_F));
    __syncthreads();

    const int la = lab[a];
    const int lane = tid & 63;
    const int pq = tid >> 6;
    const int p0 = blockIdx.y * 128 + pq * 32;

    v4f dan = *(const v4f*)(drow + lane * 4);
    v4f mb = MARGIN_F - dan;
    v4f nokv = {(lab[lane * 4 + 0] != la) ? 1.f : 0.f,
                (lab[lane * 4 + 1] != la) ? 1.f : 0.f,
                (lab[lane * 4 + 2] != la) ? 1.f : 0.f,
                (lab[lane * 4 + 3] != la) ? 1.f : 0.f};

    float* obase = out + ((size_t)a << 16) + lane * 4;
#pragma unroll 4
    for (int i = 0; i < 32; ++i) {
        int p = p0 + i;                   // wave-uniform
        v4f r = {0.f, 0.f, 0.f, 0.f};
        if (lab[p] == la) {               // wave-uniform branch
            float dap = drow[p];
            v4f t = dap + mb;
            t.x = fmaxf(t.x, EPS_F);
            t.y = fmaxf(t.y, EPS_F);
            t.z = fmaxf(t.z, EPS_F);
            t.w = fmaxf(t.w, EPS_F);
            r = t * nokv;
        }
        __builtin_nontemporal_store(r, (v4f*)(obase + (size_t)p * N));
    }
}

// ---------------- fallback path (tiny ws): dist kernel + triplet ------------
__global__ __launch_bounds__(256) void dist_kernel(const __half* __restrict__ part,
                                                   const float* __restrict__ sq,
                                                   float* __restrict__ dist) {
    const int a = blockIdx.x;
    const int tid = threadIdx.x;
    float dot = 0.f;
    const __half* base = part + a * N + tid;
#pragma unroll 8
    for (int ks = 0; ks < 32; ++ks)
        dot += __half2float(base[(size_t)ks * (N * N)]);
    dist[a * N + tid] = (tid == a) ? SQRT_EPS_F
                                   : sqrtf(fmaxf(sq[a] + sq[tid] - 2.f * dot, EPS_F));
}

__global__ __launch_bounds__(256) void triplet_kernel(const float* __restrict__ dist,
                                                      const int* __restrict__ targets,
                                                      float* __restrict__ out) {
    __shared__ __align__(16) float drow[N];
    __shared__ int lab[N];
    const int a = blockIdx.x;
    const int p0 = blockIdx.y * 16;
    const int tid = threadIdx.x;
    lab[tid] = targets[tid];
    drow[tid] = dist[a * N + tid];
    __syncthreads();

    const int la = lab[a];
    const int lane = tid & 63;
    const int pq = tid >> 6;

    v4f dan = *(const v4f*)(drow + lane * 4);
    v4f mb = MARGIN_F - dan;
    v4f nokv = {(lab[lane * 4 + 0] != la) ? 1.f : 0.f,
                (lab[lane * 4 + 1] != la) ? 1.f : 0.f,
                (lab[lane * 4 + 2] != la) ? 1.f : 0.f,
                (lab[lane * 4 + 3] != la) ? 1.f : 0.f};

    float* obase = out + ((size_t)a << 16) + lane * 4;
#pragma unroll
    for (int j = 0; j < 4; ++j) {
        int p = p0 + pq * 4 + j;
        v4f r = {0.f, 0.f, 0.f, 0.f};
        if (lab[p] == la) {
            float dap = drow[p];
            v4f t = dap + mb;
            t.x = fmaxf(t.x, EPS_F);
            t.y = fmaxf(t.y, EPS_F);
            t.z = fmaxf(t.z, EPS_F);
            t.w = fmaxf(t.w, EPS_F);
            r = t * nokv;
        }
        __builtin_nontemporal_store(r, (v4f*)(obase + (size_t)p * N));
    }
}

extern "C" void kernel_launch(void* const* d_in, const int* in_sizes, int n_in,
                              void* d_out, int out_size, void* d_ws, size_t ws_size,
                              hipStream_t stream) {
    const float* x = (const float*)d_in[0];
    const int* targets = (const int*)d_in[1];
    float* out = (float*)d_out;
    float* ws = (float*)d_ws;

    float* sq = ws;                                    // 256 floats
    size_t need_full = 1024 + (size_t)32 * N * N * sizeof(__half) + 1024;  // ~4 MB

    if (ws_size >= need_full) {
        __half* part = (__half*)(ws + 256);
        sq_kernel<<<256, 64, 0, stream>>>(x, sq);
        gram_kernel<<<dim3(4, 4, 32), 256, 0, stream>>>(x, part);
        fused_kernel<<<dim3(256, 2), 256, 0, stream>>>(part, sq, targets, out);
    } else {
        // Borrow d_out (4 MB of its 64 MB) for partials; dist lives in ws.
        // Safe: dist_kernel consumes partials before triplet_kernel writes out.
        __half* part = (__half*)d_out;
        float* dist = ws + 256;                        // 65536 floats
        sq_kernel<<<256, 64, 0, stream>>>(x, sq);
        gram_kernel<<<dim3(4, 4, 32), 256, 0, stream>>>(x, part);
        dist_kernel<<<256, 256, 0, stream>>>(part, sq, dist);
        triplet_kernel<<<dim3(256, 16), 256, 0, stream>>>(dist, targets, out);
    }
}

// Round 4
// 84.812 us; speedup vs baseline: 1.1668x; 1.0902x over previous
//
#include <hip/hip_runtime.h>
#include <hip/hip_fp16.h>

#define N 256
#define D 2048
#define MARGIN_F 0.3f
#define EPS_F 1e-12f
#define SQRT_EPS_F 1e-6f
#define KSLICES 8            // K-chunks of 256

typedef float v4f __attribute__((ext_vector_type(4)));
typedef short bf16x8 __attribute__((ext_vector_type(8)));

static __device__ __forceinline__ unsigned short f2bf_rne(float f) {
    union { float f; unsigned u; } v; v.f = f;
    unsigned r = v.u + 0x7fffu + ((v.u >> 16) & 1u);
    return (unsigned short)(r >> 16);
}

// ---- kernel 0: xb = bf16(x) (RNE) and sq[i] = sum_k x[i][k]^2 (fp32) -------
__global__ __launch_bounds__(256) void conv_sq_kernel(const float* __restrict__ x,
                                                      unsigned short* __restrict__ xb,
                                                      float* __restrict__ sq) {
    __shared__ float red[4];
    const int row = blockIdx.x;
    const int tid = threadIdx.x;
    const float* xr = x + (size_t)row * D + tid * 8;
    float4 v0 = *(const float4*)(xr);
    float4 v1 = *(const float4*)(xr + 4);
    float acc = v0.x * v0.x + v0.y * v0.y + v0.z * v0.z + v0.w * v0.w +
                v1.x * v1.x + v1.y * v1.y + v1.z * v1.z + v1.w * v1.w;
    union { unsigned short h[8]; uint4 u; } pk;
    pk.h[0] = f2bf_rne(v0.x); pk.h[1] = f2bf_rne(v0.y);
    pk.h[2] = f2bf_rne(v0.z); pk.h[3] = f2bf_rne(v0.w);
    pk.h[4] = f2bf_rne(v1.x); pk.h[5] = f2bf_rne(v1.y);
    pk.h[6] = f2bf_rne(v1.z); pk.h[7] = f2bf_rne(v1.w);
    *(uint4*)(xb + (size_t)row * D + tid * 8) = pk.u;
#pragma unroll
    for (int off = 32; off > 0; off >>= 1) acc += __shfl_down(acc, off, 64);
    if ((tid & 63) == 0) red[tid >> 6] = acc;
    __syncthreads();
    if (tid == 0) sq[row] = red[0] + red[1] + red[2] + red[3];
}

// ---- kernel 1: Gram partials via MFMA, fragments direct from L2 ------------
// grid (8,8,8): block = 32x32 tile (4 waves of 16x16), K-chunk 256.
// No LDS. part layout: part[i*(KSLICES*N) + ks*N + j], fp32.
// Gram is symmetric, so any consistent lane->k permutation in A/B cancels.
__global__ __launch_bounds__(256) void gram_mfma_kernel(const unsigned short* __restrict__ xb,
                                                        float* __restrict__ part) {
    const int w = threadIdx.x >> 6;
    const int l = threadIdx.x & 63;
    const int i0 = blockIdx.x * 32 + (w >> 1) * 16;
    const int j0 = blockIdx.y * 32 + (w & 1) * 16;
    const int ks = blockIdx.z;
    const int kq = (l >> 4) * 8;
    const unsigned short* pa = xb + (size_t)(i0 + (l & 15)) * D + ks * 256 + kq;
    const unsigned short* pb = xb + (size_t)(j0 + (l & 15)) * D + ks * 256 + kq;
    v4f acc = {0.f, 0.f, 0.f, 0.f};
#pragma unroll
    for (int t = 0; t < 8; ++t) {
        bf16x8 af = *(const bf16x8*)(pa + t * 32);
        bf16x8 bf = *(const bf16x8*)(pb + t * 32);
        acc = __builtin_amdgcn_mfma_f32_16x16x32_bf16(af, bf, acc, 0, 0, 0);
    }
    // C/D: row = (l>>4)*4 + r, col = l&15
    float* pp = part + ((size_t)(i0 + (l >> 4) * 4) * KSLICES + ks) * N + j0 + (l & 15);
#pragma unroll
    for (int r = 0; r < 4; ++r)
        pp[(size_t)r * KSLICES * N] = acc[r];
}

// ---- kernel 2: fused reduce + dist + triplet -------------------------------
// grid (256, 2). Phase 1: sum 8 contiguous fp32 slices -> dist row in LDS
// (diag forced to sqrt(eps), replicating the reference's clip branch).
// Phase 2: stream output strip with PLAIN float4 stores (NT A/B vs R3).
__global__ __launch_bounds__(256) void fused_kernel(const float* __restrict__ part,
                                                    const float* __restrict__ sq,
                                                    const int* __restrict__ targets,
                                                    float* __restrict__ out) {
    __shared__ __align__(16) float drow[N];
    __shared__ int lab[N];
    const int a = blockIdx.x;
    const int tid = threadIdx.x;
    lab[tid] = targets[tid];

    const float* pr = part + (size_t)a * (KSLICES * N);
    float dot = 0.f;
#pragma unroll
    for (int ks = 0; ks < KSLICES; ++ks)
        dot += pr[ks * N + tid];
    drow[tid] = (tid == a) ? SQRT_EPS_F
                           : sqrtf(fmaxf(sq[a] + sq[tid] - 2.f * dot, EPS_F));
    __syncthreads();

    const int la = lab[a];
    const int lane = tid & 63;
    const int pq = tid >> 6;
    const int p0 = blockIdx.y * 128 + pq * 32;

    v4f dan = *(const v4f*)(drow + lane * 4);
    v4f mb = MARGIN_F - dan;
    v4f nokv = {(lab[lane * 4 + 0] != la) ? 1.f : 0.f,
                (lab[lane * 4 + 1] != la) ? 1.f : 0.f,
                (lab[lane * 4 + 2] != la) ? 1.f : 0.f,
                (lab[lane * 4 + 3] != la) ? 1.f : 0.f};

    float* obase = out + ((size_t)a << 16) + lane * 4;
#pragma unroll 4
    for (int i = 0; i < 32; ++i) {
        int p = p0 + i;                   // wave-uniform
        v4f r = {0.f, 0.f, 0.f, 0.f};
        if (lab[p] == la) {               // wave-uniform branch
            float dap = drow[p];
            v4f t = dap + mb;
            t.x = fmaxf(t.x, EPS_F);
            t.y = fmaxf(t.y, EPS_F);
            t.z = fmaxf(t.z, EPS_F);
            t.w = fmaxf(t.w, EPS_F);
            r = t * nokv;
        }
        *(v4f*)(obase + (size_t)p * N) = r;
    }
}

// ---------------- fallback path (tiny ws): R3 VALU pipeline -----------------
__global__ __launch_bounds__(64) void sq_kernel(const float* __restrict__ x,
                                                float* __restrict__ sq) {
    int row = blockIdx.x;
    int lane = threadIdx.x;
    const float4* xr = (const float4*)(x + (size_t)row * D);
    float acc = 0.f;
#pragma unroll
    for (int it = 0; it < 8; ++it) {
        float4 v = xr[lane + 64 * it];
        acc += v.x * v.x + v.y * v.y + v.z * v.z + v.w * v.w;
    }
#pragma unroll
    for (int off = 32; off > 0; off >>= 1) acc += __shfl_down(acc, off, 64);
    if (lane == 0) sq[row] = acc;
}

__global__ __launch_bounds__(256) void gram_valu_kernel(const float* __restrict__ x,
                                                        __half* __restrict__ part) {
    __shared__ __align__(16) float As[64 * 68];
    __shared__ __align__(16) float Bs[64 * 68];
    const int i0 = blockIdx.x * 64, j0 = blockIdx.y * 64, k0 = blockIdx.z * 64;
    const int tid = threadIdx.x;
#pragma unroll
    for (int it = 0; it < 4; ++it) {
        int f = tid + 256 * it;
        int row = f >> 4;
        int c4 = f & 15;
        int sc4 = c4 ^ ((row >> 2) & 15);
        float4 va = *(const float4*)(x + (size_t)(i0 + row) * D + k0 + c4 * 4);
        float4 vb = *(const float4*)(x + (size_t)(j0 + row) * D + k0 + c4 * 4);
        *(float4*)(As + row * 68 + sc4 * 4) = va;
        *(float4*)(Bs + row * 68 + sc4 * 4) = vb;
    }
    __syncthreads();
    const int tx = tid & 15, ty = tid >> 4;
    float acc[4][4];
#pragma unroll
    for (int r = 0; r < 4; ++r)
#pragma unroll
        for (int c = 0; c < 4; ++c) acc[r][c] = 0.f;
#pragma unroll
    for (int k4 = 0; k4 < 16; ++k4) {
        float4 a[4], b[4];
        const int ca = (k4 ^ ty) << 2, cb = (k4 ^ tx) << 2;
#pragma unroll
        for (int r = 0; r < 4; ++r) {
            a[r] = *(const float4*)(As + (ty * 4 + r) * 68 + ca);
            b[r] = *(const float4*)(Bs + (tx * 4 + r) * 68 + cb);
        }
#pragma unroll
        for (int r = 0; r < 4; ++r)
#pragma unroll
            for (int c = 0; c < 4; ++c)
                acc[r][c] += a[r].x * b[c].x + a[r].y * b[c].y +
                             a[r].z * b[c].z + a[r].w * b[c].w;
    }
    __half* pout = part + (size_t)blockIdx.z * (N * N);
#pragma unroll
    for (int r = 0; r < 4; ++r) {
        int gi = i0 + ty * 4 + r;
        union { __half2 h2[2]; uint2 u; } pk;
        pk.h2[0] = __floats2half2_rn(acc[r][0], acc[r][1]);
        pk.h2[1] = __floats2half2_rn(acc[r][2], acc[r][3]);
        *(uint2*)(pout + (size_t)gi * N + j0 + tx * 4) = pk.u;
    }
}

__global__ __launch_bounds__(256) void dist_kernel(const __half* __restrict__ part,
                                                   const float* __restrict__ sq,
                                                   float* __restrict__ dist) {
    const int a = blockIdx.x;
    const int tid = threadIdx.x;
    float dot = 0.f;
    const __half* base = part + a * N + tid;
#pragma unroll 8
    for (int ks = 0; ks < 32; ++ks)
        dot += __half2float(base[(size_t)ks * (N * N)]);
    dist[a * N + tid] = (tid == a) ? SQRT_EPS_F
                                   : sqrtf(fmaxf(sq[a] + sq[tid] - 2.f * dot, EPS_F));
}

__global__ __launch_bounds__(256) void triplet_kernel(const float* __restrict__ dist,
                                                      const int* __restrict__ targets,
                                                      float* __restrict__ out) {
    __shared__ __align__(16) float drow[N];
    __shared__ int lab[N];
    const int a = blockIdx.x;
    const int p0 = blockIdx.y * 16;
    const int tid = threadIdx.x;
    lab[tid] = targets[tid];
    drow[tid] = dist[a * N + tid];
    __syncthreads();
    const int la = lab[a];
    const int lane = tid & 63;
    const int pq = tid >> 6;
    v4f dan = *(const v4f*)(drow + lane * 4);
    v4f mb = MARGIN_F - dan;
    v4f nokv = {(lab[lane * 4 + 0] != la) ? 1.f : 0.f,
                (lab[lane * 4 + 1] != la) ? 1.f : 0.f,
                (lab[lane * 4 + 2] != la) ? 1.f : 0.f,
                (lab[lane * 4 + 3] != la) ? 1.f : 0.f};
    float* obase = out + ((size_t)a << 16) + lane * 4;
#pragma unroll
    for (int j = 0; j < 4; ++j) {
        int p = p0 + pq * 4 + j;
        v4f r = {0.f, 0.f, 0.f, 0.f};
        if (lab[p] == la) {
            float dap = drow[p];
            v4f t = dap + mb;
            t.x = fmaxf(t.x, EPS_F);
            t.y = fmaxf(t.y, EPS_F);
            t.z = fmaxf(t.z, EPS_F);
            t.w = fmaxf(t.w, EPS_F);
            r = t * nokv;
        }
        *(v4f*)(obase + (size_t)p * N) = r;
    }
}

extern "C" void kernel_launch(void* const* d_in, const int* in_sizes, int n_in,
                              void* d_out, int out_size, void* d_ws, size_t ws_size,
                              hipStream_t stream) {
    const float* x = (const float*)d_in[0];
    const int* targets = (const int*)d_in[1];
    float* out = (float*)d_out;
    float* ws = (float*)d_ws;

    // ws layout (full path): sq[256] | xb[256*2048 bf16 = 1MB] | part[8*256*256 fp32 = 2MB]
    float* sq = ws;
    unsigned short* xb = (unsigned short*)(ws + 256);
    float* part = (float*)(xb + (size_t)N * D);
    size_t need = 256 * 4 + (size_t)N * D * 2 + (size_t)KSLICES * N * N * 4 + 1024;

    if (ws_size >= need) {
        conv_sq_kernel<<<256, 256, 0, stream>>>(x, xb, sq);
        gram_mfma_kernel<<<dim3(8, 8, 8), 256, 0, stream>>>(xb, part);
        fused_kernel<<<dim3(256, 2), 256, 0, stream>>>(part, sq, targets, out);
    } else {
        // Borrow d_out (4 MB of 64 MB) for fp16 partials; dist lives in ws.
        __half* hpart = (__half*)d_out;
        float* dist = ws + 256;
        sq_kernel<<<256, 64, 0, stream>>>(x, sq);
        gram_valu_kernel<<<dim3(4, 4, 32), 256, 0, stream>>>(x, hpart);
        dist_kernel<<<256, 256, 0, stream>>>(hpart, sq, dist);
        triplet_kernel<<<dim3(256, 16), 256, 0, stream>>>(dist, targets, out);
    }
}